// Round 1
// baseline (947.340 us; speedup 1.0000x reference)
//
#include <hip/hip_runtime.h>
#include <hip/hip_bf16.h>
#include <cstdint>

// GCN encoder: h = relu(segsum((x@W1)[src], dst) + b1)
//              mu = segsum((h@W2)[src],dst)+b2 ; logvar = segsum((h@W3)[src],dst)+b3
// Rewrite: segsum((h@W)[src]) == segsum(h[src]) @ W  -> aggregate once (128-d),
// then one fused GEMM with [W2|W3].
//
// Pipeline: detect idx dtype -> build CSR by dst (counts/scan/fill) ->
//           gemm1 (x@W1 -> h0) -> seg1 (agg+b1+relu -> h) ->
//           seg2 (agg h -> agg2) -> gemm2 (agg2@[W2|W3]+[b2|b3] -> d_out)

#define INC  256
#define HIDC 128
#define OUTC 64

__device__ __forceinline__ int load_idx(const void* p, long long i, int is64) {
  if (is64) return (int)((const long long*)p)[i];
  return ((const int*)p)[i];
}

// Detect whether edge_index is int64 (all "high words" zero) or int32.
__global__ void detect_kernel(const unsigned int* __restrict__ p, int* __restrict__ flag) {
  __shared__ int nz;
  if (threadIdx.x == 0) nz = 0;
  __syncthreads();
  unsigned int w = p[2 * threadIdx.x + 1];
  if (w) atomicAdd(&nz, 1);
  __syncthreads();
  if (threadIdx.x == 0) *flag = (nz == 0) ? 1 : 0;  // 1 => int64
}

__global__ void zero_int_kernel(int* __restrict__ p, int n) {
  int i = blockIdx.x * blockDim.x + threadIdx.x;
  if (i < n) p[i] = 0;
}

__global__ void count_kernel(const void* __restrict__ eidx, int E,
                             const int* __restrict__ flag, int* __restrict__ counts) {
  int is64 = *flag;
  int stride = gridDim.x * blockDim.x;
  for (int e = blockIdx.x * blockDim.x + threadIdx.x; e < E; e += stride) {
    int d = load_idx(eidx, (long long)E + e, is64);
    atomicAdd(&counts[d], 1);
  }
}

// Single-block exclusive scan over counts[0..N) -> offsets[0..N]
__global__ void scan_kernel(const int* __restrict__ counts, int* __restrict__ offsets, int N) {
  __shared__ int sums[1024];
  int t = threadIdx.x;
  int per = (N + 1023) >> 10;
  int lo = t * per;
  int hi = min(lo + per, N);
  int s = 0;
  for (int i = lo; i < hi; i++) s += counts[i];
  sums[t] = s;
  __syncthreads();
  // Hillis-Steele inclusive scan
  for (int off = 1; off < 1024; off <<= 1) {
    int v = (t >= off) ? sums[t - off] : 0;
    __syncthreads();
    sums[t] += v;
    __syncthreads();
  }
  int run = (t == 0) ? 0 : sums[t - 1];
  for (int i = lo; i < hi; i++) { offsets[i] = run; run += counts[i]; }
  if (t == 1023) offsets[N] = sums[1023];
}

__global__ void fill_kernel(const void* __restrict__ eidx, int E,
                            const int* __restrict__ flag, const int* __restrict__ offsets,
                            int* __restrict__ cursor, int* __restrict__ csr_src) {
  int is64 = *flag;
  int stride = gridDim.x * blockDim.x;
  for (int e = blockIdx.x * blockDim.x + threadIdx.x; e < E; e += stride) {
    int s = load_idx(eidx, e, is64);
    int d = load_idx(eidx, (long long)E + e, is64);
    int p = atomicAdd(&cursor[d], 1);
    csr_src[offsets[d] + p] = s;
  }
}

// Tiled fp32 GEMM: A[M,K] @ B[K,128] (+optional split/bias epilogue).
// BM=64, BN=128, BK=32, 256 threads, each thread computes 4x8 outputs.
template <int K, bool SPLIT>
__global__ __launch_bounds__(256, 2) void gemm_kernel(
    const float* __restrict__ A, const float* __restrict__ B0,
    const float* __restrict__ B1, const float* __restrict__ bias0,
    const float* __restrict__ bias1, float* __restrict__ out, int M, int Nn) {
  __shared__ float As[64][33];   // +1 pad
  __shared__ float Bs[32][128];
  const int tid = threadIdx.x;
  const int tx = tid & 15;   // col group: cols tx*8..tx*8+7
  const int ty = tid >> 4;   // row group: rows ty*4..ty*4+3
  const int bm = blockIdx.x * 64;

  float acc[4][8];
#pragma unroll
  for (int i = 0; i < 4; i++)
#pragma unroll
    for (int j = 0; j < 8; j++) acc[i][j] = 0.f;

  for (int k0 = 0; k0 < K; k0 += 32) {
    // A tile: 64 rows x 32 cols = 512 float4, 2 per thread
#pragma unroll
    for (int f = tid; f < 512; f += 256) {
      int r = f >> 3, c4 = f & 7;
      int row = bm + r;
      float4 v = make_float4(0.f, 0.f, 0.f, 0.f);
      if (row < M) v = *(const float4*)(A + (long long)row * K + k0 + c4 * 4);
      As[r][c4 * 4 + 0] = v.x;
      As[r][c4 * 4 + 1] = v.y;
      As[r][c4 * 4 + 2] = v.z;
      As[r][c4 * 4 + 3] = v.w;
    }
    // B tile: 32 rows x 128 cols = 1024 float4, 4 per thread
#pragma unroll
    for (int f = tid; f < 1024; f += 256) {
      int r = f >> 5, c4 = f & 31;
      int k = k0 + r;
      int c = c4 * 4;
      float4 v;
      if (!SPLIT) {
        v = *(const float4*)(B0 + (long long)k * 128 + c);
      } else {
        const float* Bp = (c < 64) ? (B0 + (long long)k * 64 + c)
                                   : (B1 + (long long)k * 64 + (c - 64));
        v = *(const float4*)Bp;
      }
      *(float4*)&Bs[r][c] = v;
    }
    __syncthreads();
#pragma unroll
    for (int kk = 0; kk < 32; kk++) {
      float a[4], b[8];
#pragma unroll
      for (int i = 0; i < 4; i++) a[i] = As[ty * 4 + i][kk];
#pragma unroll
      for (int j = 0; j < 8; j++) b[j] = Bs[kk][tx * 8 + j];
#pragma unroll
      for (int i = 0; i < 4; i++)
#pragma unroll
        for (int j = 0; j < 8; j++) acc[i][j] = fmaf(a[i], b[j], acc[i][j]);
    }
    __syncthreads();
  }

#pragma unroll
  for (int i = 0; i < 4; i++) {
    int row = bm + ty * 4 + i;
    if (row >= M) continue;
    int c0 = tx * 8;  // 8-col group never crosses the 64-col boundary
    if (!SPLIT) {
      float4 v0 = make_float4(acc[i][0], acc[i][1], acc[i][2], acc[i][3]);
      float4 v1 = make_float4(acc[i][4], acc[i][5], acc[i][6], acc[i][7]);
      *(float4*)(out + (long long)row * 128 + c0) = v0;
      *(float4*)(out + (long long)row * 128 + c0 + 4) = v1;
    } else {
      const float* bb = (c0 < 64) ? bias0 : bias1;
      int cb = c0 & 63;
      long long base = (c0 < 64) ? ((long long)row * 64 + c0)
                                 : ((long long)Nn * 64 + (long long)row * 64 + (c0 - 64));
      float4 v0 = make_float4(acc[i][0] + bb[cb + 0], acc[i][1] + bb[cb + 1],
                              acc[i][2] + bb[cb + 2], acc[i][3] + bb[cb + 3]);
      float4 v1 = make_float4(acc[i][4] + bb[cb + 4], acc[i][5] + bb[cb + 5],
                              acc[i][6] + bb[cb + 6], acc[i][7] + bb[cb + 7]);
      *(float4*)(out + base) = v0;
      *(float4*)(out + base + 4) = v1;
    }
  }
}

// Block-per-node CSR aggregation: out[n][c] = sum_{e in in(n)} feat[src(e)][c]
template <bool RELU>
__global__ __launch_bounds__(128) void seg_kernel(
    const float* __restrict__ feat, const int* __restrict__ offsets,
    const int* __restrict__ csr_src, const float* __restrict__ bias,
    float* __restrict__ out, int Nn) {
  int n = blockIdx.x;
  int c = threadIdx.x;
  int lo = offsets[n], hi = offsets[n + 1];
  float acc = 0.f;
  for (int i = lo; i < hi; i++) {
    int s = csr_src[i];  // uniform across block -> scalar load
    acc += feat[s * HIDC + c];
  }
  if (RELU) {
    acc += bias[c];
    acc = fmaxf(acc, 0.f);
  }
  out[n * HIDC + c] = acc;
}

extern "C" void kernel_launch(void* const* d_in, const int* in_sizes, int n_in,
                              void* d_out, int out_size, void* d_ws, size_t ws_size,
                              hipStream_t stream) {
  const float* x  = (const float*)d_in[0];
  const void*  ei = d_in[1];
  const float* W1 = (const float*)d_in[2];
  const float* b1 = (const float*)d_in[3];
  const float* W2 = (const float*)d_in[4];
  const float* b2 = (const float*)d_in[5];
  const float* W3 = (const float*)d_in[6];
  const float* b3 = (const float*)d_in[7];
  float* out = (float*)d_out;

  const int Nn = in_sizes[0] / INC;  // 100000
  const int E  = in_sizes[1] / 2;    // 1600000

  // Workspace layout (~110 MB)
  float* h0 = (float*)d_ws;                         // Nn*128
  float* h  = h0 + (size_t)Nn * HIDC;               // Nn*128
  float* agg2 = h0;                                 // reuse h0 (dead after seg1)
  int* offsets = (int*)(h + (size_t)Nn * HIDC);     // Nn+1
  int* cnt     = offsets + (Nn + 1);                // Nn (counts, then cursor)
  int* csr     = cnt + Nn;                          // E
  int* flag    = csr + E;                           // 1

  const int zb = (Nn + 255) / 256;
  const int eb = 2048;

  hipLaunchKernelGGL(detect_kernel, dim3(1), dim3(256), 0, stream,
                     (const unsigned int*)ei, flag);
  hipLaunchKernelGGL(zero_int_kernel, dim3(zb), dim3(256), 0, stream, cnt, Nn);
  hipLaunchKernelGGL(count_kernel, dim3(eb), dim3(256), 0, stream, ei, E, flag, cnt);
  hipLaunchKernelGGL(scan_kernel, dim3(1), dim3(1024), 0, stream, cnt, offsets, Nn);
  hipLaunchKernelGGL(zero_int_kernel, dim3(zb), dim3(256), 0, stream, cnt, Nn);
  hipLaunchKernelGGL(fill_kernel, dim3(eb), dim3(256), 0, stream, ei, E, flag,
                     offsets, cnt, csr);

  const int mg = (Nn + 63) / 64;
  hipLaunchKernelGGL((gemm_kernel<INC, false>), dim3(mg), dim3(256), 0, stream,
                     x, W1, nullptr, nullptr, nullptr, h0, Nn, Nn);
  hipLaunchKernelGGL((seg_kernel<true>), dim3(Nn), dim3(HIDC), 0, stream,
                     h0, offsets, csr, b1, h, Nn);
  hipLaunchKernelGGL((seg_kernel<false>), dim3(Nn), dim3(HIDC), 0, stream,
                     h, offsets, csr, nullptr, agg2, Nn);
  hipLaunchKernelGGL((gemm_kernel<HIDC, true>), dim3(mg), dim3(256), 0, stream,
                     agg2, W2, W3, b2, b3, out, Nn, Nn);
}

// Round 4
// 830.575 us; speedup vs baseline: 1.1406x; 1.1406x over previous
//
#include <hip/hip_runtime.h>
#include <hip/hip_bf16.h>
#include <cstdint>

// GCN encoder: h = relu(segsum((x@W1)[src], dst) + b1)
//              mu = segsum((h@W2)[src],dst)+b2 ; logvar = segsum((h@W3)[src],dst)+b3
// Rewrite: segsum((h@W)[src]) == segsum(h[src]) @ W  -> aggregate once (128-d),
// then one fused GEMM with [W2|W3].
//
// R1 (re-submitted R2, R3; R1/R2 benches were infra acquisition timeouts):
// seg_kernel = wave-per-node, float2/lane, edge-unroll x4 (R0 measurement:
// latency-bound at 2.56 TB/s path BW, VALUBusy 13%, 0 bank conflicts).
// GEMM: transposed A-tile in LDS -> ds_read_b128 fragment reads.

#define INC  256
#define HIDC 128
#define OUTC 64

__device__ __forceinline__ int load_idx(const void* p, long long i, int is64) {
  if (is64) return (int)((const long long*)p)[i];
  return ((const int*)p)[i];
}

// Detect whether edge_index is int64 (all "high words" zero) or int32.
__global__ void detect_kernel(const unsigned int* __restrict__ p, int* __restrict__ flag) {
  __shared__ int nz;
  if (threadIdx.x == 0) nz = 0;
  __syncthreads();
  unsigned int w = p[2 * threadIdx.x + 1];
  if (w) atomicAdd(&nz, 1);
  __syncthreads();
  if (threadIdx.x == 0) *flag = (nz == 0) ? 1 : 0;  // 1 => int64
}

__global__ void zero_int_kernel(int* __restrict__ p, int n) {
  int i = blockIdx.x * blockDim.x + threadIdx.x;
  if (i < n) p[i] = 0;
}

__global__ void count_kernel(const void* __restrict__ eidx, int E,
                             const int* __restrict__ flag, int* __restrict__ counts) {
  int is64 = *flag;
  int stride = gridDim.x * blockDim.x;
  for (int e = blockIdx.x * blockDim.x + threadIdx.x; e < E; e += stride) {
    int d = load_idx(eidx, (long long)E + e, is64);
    atomicAdd(&counts[d], 1);
  }
}

// Single-block exclusive scan over counts[0..N) -> offsets[0..N]
__global__ void scan_kernel(const int* __restrict__ counts, int* __restrict__ offsets, int N) {
  __shared__ int sums[1024];
  int t = threadIdx.x;
  int per = (N + 1023) >> 10;
  int lo = t * per;
  int hi = min(lo + per, N);
  int s = 0;
  for (int i = lo; i < hi; i++) s += counts[i];
  sums[t] = s;
  __syncthreads();
  for (int off = 1; off < 1024; off <<= 1) {
    int v = (t >= off) ? sums[t - off] : 0;
    __syncthreads();
    sums[t] += v;
    __syncthreads();
  }
  int run = (t == 0) ? 0 : sums[t - 1];
  for (int i = lo; i < hi; i++) { offsets[i] = run; run += counts[i]; }
  if (t == 1023) offsets[N] = sums[1023];
}

__global__ void fill_kernel(const void* __restrict__ eidx, int E,
                            const int* __restrict__ flag, const int* __restrict__ offsets,
                            int* __restrict__ cursor, int* __restrict__ csr_src) {
  int is64 = *flag;
  int stride = gridDim.x * blockDim.x;
  for (int e = blockIdx.x * blockDim.x + threadIdx.x; e < E; e += stride) {
    int s = load_idx(eidx, e, is64);
    int d = load_idx(eidx, (long long)E + e, is64);
    int p = atomicAdd(&cursor[d], 1);
    csr_src[offsets[d] + p] = s;
  }
}

// Tiled fp32 GEMM: A[M,K] @ B[K,128] (+optional split/bias epilogue).
// BM=64, BN=128, BK=32, 256 threads, each thread computes 4x8 outputs.
// A-tile stored TRANSPOSED (AsT[kk][row]) so fragment reads are ds_read_b128.
template <int K, bool SPLIT>
__global__ __launch_bounds__(256, 2) void gemm_kernel(
    const float* __restrict__ A, const float* __restrict__ B0,
    const float* __restrict__ B1, const float* __restrict__ bias0,
    const float* __restrict__ bias1, float* __restrict__ out, int M, int Nn) {
  __shared__ float AsT[32][68];  // [kk][row], stride 68: 16B-aligned rows
  __shared__ float Bs[32][128];
  const int tid = threadIdx.x;
  const int tx = tid & 15;   // col group: cols tx*8..tx*8+7
  const int ty = tid >> 4;   // row group: rows ty*4..ty*4+3
  const int bm = blockIdx.x * 64;

  float acc[4][8];
#pragma unroll
  for (int i = 0; i < 4; i++)
#pragma unroll
    for (int j = 0; j < 8; j++) acc[i][j] = 0.f;

  for (int k0 = 0; k0 < K; k0 += 32) {
    // A tile: 64 rows x 32 cols = 512 float4, 2 per thread; store transposed
#pragma unroll
    for (int f = tid; f < 512; f += 256) {
      int r = f >> 3, c4 = f & 7;
      int row = bm + r;
      float4 v = make_float4(0.f, 0.f, 0.f, 0.f);
      if (row < M) v = *(const float4*)(A + (long long)row * K + k0 + c4 * 4);
      AsT[c4 * 4 + 0][r] = v.x;
      AsT[c4 * 4 + 1][r] = v.y;
      AsT[c4 * 4 + 2][r] = v.z;
      AsT[c4 * 4 + 3][r] = v.w;
    }
    // B tile: 32 rows x 128 cols = 1024 float4, 4 per thread
#pragma unroll
    for (int f = tid; f < 1024; f += 256) {
      int r = f >> 5, c4 = f & 31;
      int k = k0 + r;
      int c = c4 * 4;
      float4 v;
      if (!SPLIT) {
        v = *(const float4*)(B0 + (long long)k * 128 + c);
      } else {
        const float* Bp = (c < 64) ? (B0 + (long long)k * 64 + c)
                                   : (B1 + (long long)k * 64 + (c - 64));
        v = *(const float4*)Bp;
      }
      *(float4*)&Bs[r][c] = v;
    }
    __syncthreads();
#pragma unroll
    for (int kk = 0; kk < 32; kk++) {
      float4 av = *(const float4*)(&AsT[kk][ty * 4]);
      float4 b0 = *(const float4*)(&Bs[kk][tx * 8]);
      float4 b1 = *(const float4*)(&Bs[kk][tx * 8 + 4]);
      float a[4] = {av.x, av.y, av.z, av.w};
      float b[8] = {b0.x, b0.y, b0.z, b0.w, b1.x, b1.y, b1.z, b1.w};
#pragma unroll
      for (int i = 0; i < 4; i++)
#pragma unroll
        for (int j = 0; j < 8; j++) acc[i][j] = fmaf(a[i], b[j], acc[i][j]);
    }
    __syncthreads();
  }

#pragma unroll
  for (int i = 0; i < 4; i++) {
    int row = bm + ty * 4 + i;
    if (row >= M) continue;
    int c0 = tx * 8;  // 8-col group never crosses the 64-col boundary
    if (!SPLIT) {
      float4 v0 = make_float4(acc[i][0], acc[i][1], acc[i][2], acc[i][3]);
      float4 v1 = make_float4(acc[i][4], acc[i][5], acc[i][6], acc[i][7]);
      *(float4*)(out + (long long)row * 128 + c0) = v0;
      *(float4*)(out + (long long)row * 128 + c0 + 4) = v1;
    } else {
      const float* bb = (c0 < 64) ? bias0 : bias1;
      int cb = c0 & 63;
      long long base = (c0 < 64) ? ((long long)row * 64 + c0)
                                 : ((long long)Nn * 64 + (long long)row * 64 + (c0 - 64));
      float4 v0 = make_float4(acc[i][0] + bb[cb + 0], acc[i][1] + bb[cb + 1],
                              acc[i][2] + bb[cb + 2], acc[i][3] + bb[cb + 3]);
      float4 v1 = make_float4(acc[i][4] + bb[cb + 4], acc[i][5] + bb[cb + 5],
                              acc[i][6] + bb[cb + 6], acc[i][7] + bb[cb + 7]);
      *(float4*)(out + base) = v0;
      *(float4*)(out + base + 4) = v1;
    }
  }
}

// Wave-per-node CSR aggregation: out[n][c] = sum_{e in in(n)} feat[src(e)][c]
// Lane c loads float2 (channels 2c, 2c+1); edge loop unrolled x4 so each wave
// keeps 4 independent 512B loads in flight.
template <bool RELU>
__global__ __launch_bounds__(256) void seg_kernel(
    const float* __restrict__ feat, const int* __restrict__ offsets,
    const int* __restrict__ csr_src, const float* __restrict__ bias,
    float* __restrict__ out, int Nn) {
  int n = blockIdx.x * 4 + (threadIdx.x >> 6);
  int lane = threadIdx.x & 63;
  if (n >= Nn) return;
  int lo = offsets[n], hi = offsets[n + 1];
  int c = lane << 1;  // channel pair
  float ax = 0.f, ay = 0.f;
  int i = lo;
  for (; i + 4 <= hi; i += 4) {
    int s0 = csr_src[i];
    int s1 = csr_src[i + 1];
    int s2 = csr_src[i + 2];
    int s3 = csr_src[i + 3];
    float2 v0 = *(const float2*)(feat + (size_t)s0 * HIDC + c);
    float2 v1 = *(const float2*)(feat + (size_t)s1 * HIDC + c);
    float2 v2 = *(const float2*)(feat + (size_t)s2 * HIDC + c);
    float2 v3 = *(const float2*)(feat + (size_t)s3 * HIDC + c);
    ax += v0.x + v1.x + v2.x + v3.x;
    ay += v0.y + v1.y + v2.y + v3.y;
  }
  for (; i < hi; i++) {
    int s = csr_src[i];
    float2 v = *(const float2*)(feat + (size_t)s * HIDC + c);
    ax += v.x;
    ay += v.y;
  }
  if (RELU) {
    ax = fmaxf(ax + bias[c], 0.f);
    ay = fmaxf(ay + bias[c + 1], 0.f);
  }
  *(float2*)(out + (size_t)n * HIDC + c) = make_float2(ax, ay);
}

extern "C" void kernel_launch(void* const* d_in, const int* in_sizes, int n_in,
                              void* d_out, int out_size, void* d_ws, size_t ws_size,
                              hipStream_t stream) {
  const float* x  = (const float*)d_in[0];
  const void*  ei = d_in[1];
  const float* W1 = (const float*)d_in[2];
  const float* b1 = (const float*)d_in[3];
  const float* W2 = (const float*)d_in[4];
  const float* b2 = (const float*)d_in[5];
  const float* W3 = (const float*)d_in[6];
  const float* b3 = (const float*)d_in[7];
  float* out = (float*)d_out;

  const int Nn = in_sizes[0] / INC;  // 100000
  const int E  = in_sizes[1] / 2;    // 1600000

  // Workspace layout (~110 MB)
  float* h0 = (float*)d_ws;                         // Nn*128
  float* h  = h0 + (size_t)Nn * HIDC;               // Nn*128
  float* agg2 = h0;                                 // reuse h0 (dead after seg1)
  int* offsets = (int*)(h + (size_t)Nn * HIDC);     // Nn+1
  int* cnt     = offsets + (Nn + 1);                // Nn (counts, then cursor)
  int* csr     = cnt + Nn;                          // E
  int* flag    = csr + E;                           // 1

  const int zb = (Nn + 255) / 256;
  const int eb = 2048;

  hipLaunchKernelGGL(detect_kernel, dim3(1), dim3(256), 0, stream,
                     (const unsigned int*)ei, flag);
  hipLaunchKernelGGL(zero_int_kernel, dim3(zb), dim3(256), 0, stream, cnt, Nn);
  hipLaunchKernelGGL(count_kernel, dim3(eb), dim3(256), 0, stream, ei, E, flag, cnt);
  hipLaunchKernelGGL(scan_kernel, dim3(1), dim3(1024), 0, stream, cnt, offsets, Nn);
  hipLaunchKernelGGL(zero_int_kernel, dim3(zb), dim3(256), 0, stream, cnt, Nn);
  hipLaunchKernelGGL(fill_kernel, dim3(eb), dim3(256), 0, stream, ei, E, flag,
                     offsets, cnt, csr);

  const int mg = (Nn + 63) / 64;
  const int sg = (Nn + 3) / 4;
  hipLaunchKernelGGL((gemm_kernel<INC, false>), dim3(mg), dim3(256), 0, stream,
                     x, W1, nullptr, nullptr, nullptr, h0, Nn, Nn);
  hipLaunchKernelGGL((seg_kernel<true>), dim3(sg), dim3(256), 0, stream,
                     h0, offsets, csr, b1, h, Nn);
  hipLaunchKernelGGL((seg_kernel<false>), dim3(sg), dim3(256), 0, stream,
                     h, offsets, csr, nullptr, agg2, Nn);
  hipLaunchKernelGGL((gemm_kernel<HIDC, true>), dim3(mg), dim3(256), 0, stream,
                     agg2, W2, W3, b2, b3, out, Nn, Nn);
}

// Round 5
// 674.484 us; speedup vs baseline: 1.4045x; 1.2314x over previous
//
#include <hip/hip_runtime.h>
#include <hip/hip_bf16.h>
#include <cstdint>

// GCN encoder: h = relu(segsum((x@W1)[src], dst) + b1)
//              mu = segsum((h@W2)[src],dst)+b2 ; logvar = segsum((h@W3)[src],dst)+b3
// Rewrite: segsum((h@W)[src]) == segsum(h[src]) @ W  -> aggregate once (128-d),
// then one fused GEMM with [W2|W3].
//
// R4: single-block scan_kernel (164 us, 0.16% occupancy, fully latency-bound)
// replaced by 3-level hierarchical scan (block_sum / scan_blocksums /
// scan_local), one element per thread, coalesced. Everything else unchanged
// from R1 for clean attribution.

#define INC  256
#define HIDC 128
#define OUTC 64

__device__ __forceinline__ int load_idx(const void* p, long long i, int is64) {
  if (is64) return (int)((const long long*)p)[i];
  return ((const int*)p)[i];
}

// Detect whether edge_index is int64 (all "high words" zero) or int32.
__global__ void detect_kernel(const unsigned int* __restrict__ p, int* __restrict__ flag) {
  __shared__ int nz;
  if (threadIdx.x == 0) nz = 0;
  __syncthreads();
  unsigned int w = p[2 * threadIdx.x + 1];
  if (w) atomicAdd(&nz, 1);
  __syncthreads();
  if (threadIdx.x == 0) *flag = (nz == 0) ? 1 : 0;  // 1 => int64
}

__global__ void zero_int_kernel(int* __restrict__ p, int n) {
  int i = blockIdx.x * blockDim.x + threadIdx.x;
  if (i < n) p[i] = 0;
}

__global__ void count_kernel(const void* __restrict__ eidx, int E,
                             const int* __restrict__ flag, int* __restrict__ counts) {
  int is64 = *flag;
  int stride = gridDim.x * blockDim.x;
  for (int e = blockIdx.x * blockDim.x + threadIdx.x; e < E; e += stride) {
    int d = load_idx(eidx, (long long)E + e, is64);
    atomicAdd(&counts[d], 1);
  }
}

// ---- 3-level hierarchical exclusive scan over counts[0..N) -> offsets[0..N]
// Level 1: per-block (256-wide) sums.
__global__ __launch_bounds__(256) void block_sum_kernel(
    const int* __restrict__ counts, int* __restrict__ block_sums, int N) {
  int b = blockIdx.x, t = threadIdx.x;
  int i = b * 256 + t;
  int v = (i < N) ? counts[i] : 0;
#pragma unroll
  for (int off = 32; off >= 1; off >>= 1) v += __shfl_down(v, off, 64);
  __shared__ int ws_[4];
  if ((t & 63) == 0) ws_[t >> 6] = v;
  __syncthreads();
  if (t == 0) block_sums[b] = ws_[0] + ws_[1] + ws_[2] + ws_[3];
}

// Level 2: single-block exclusive scan of block_sums[0..SB) (SB <= 512).
__global__ __launch_bounds__(512) void scan_blocksums_kernel(
    const int* __restrict__ block_sums, int* __restrict__ block_base, int SB) {
  __shared__ int buf[512];
  int t = threadIdx.x;
  int self = (t < SB) ? block_sums[t] : 0;
  buf[t] = self;
  __syncthreads();
#pragma unroll
  for (int off = 1; off < 512; off <<= 1) {
    int x = (t >= off) ? buf[t - off] : 0;
    __syncthreads();
    buf[t] += x;
    __syncthreads();
  }
  if (t < SB) block_base[t] = buf[t] - self;  // exclusive
}

// Level 3: per-block local scan + base -> offsets; last element writes offsets[N].
__global__ __launch_bounds__(256) void scan_local_kernel(
    const int* __restrict__ counts, const int* __restrict__ block_base,
    int* __restrict__ offsets, int N) {
  __shared__ int buf[256];
  int b = blockIdx.x, t = threadIdx.x;
  int i = b * 256 + t;
  int self = (i < N) ? counts[i] : 0;
  buf[t] = self;
  __syncthreads();
#pragma unroll
  for (int off = 1; off < 256; off <<= 1) {
    int x = (t >= off) ? buf[t - off] : 0;
    __syncthreads();
    buf[t] += x;
    __syncthreads();
  }
  int incl = buf[t] + block_base[b];
  if (i < N) offsets[i] = incl - self;  // exclusive
  if (i == N - 1) offsets[N] = incl;    // total = E
}

__global__ void fill_kernel(const void* __restrict__ eidx, int E,
                            const int* __restrict__ flag, const int* __restrict__ offsets,
                            int* __restrict__ cursor, int* __restrict__ csr_src) {
  int is64 = *flag;
  int stride = gridDim.x * blockDim.x;
  for (int e = blockIdx.x * blockDim.x + threadIdx.x; e < E; e += stride) {
    int s = load_idx(eidx, e, is64);
    int d = load_idx(eidx, (long long)E + e, is64);
    int p = atomicAdd(&cursor[d], 1);
    csr_src[offsets[d] + p] = s;
  }
}

// Tiled fp32 GEMM: A[M,K] @ B[K,128] (+optional split/bias epilogue).
// BM=64, BN=128, BK=32, 256 threads, each thread computes 4x8 outputs.
// A-tile stored TRANSPOSED (AsT[kk][row]) so fragment reads are ds_read_b128.
template <int K, bool SPLIT>
__global__ __launch_bounds__(256, 2) void gemm_kernel(
    const float* __restrict__ A, const float* __restrict__ B0,
    const float* __restrict__ B1, const float* __restrict__ bias0,
    const float* __restrict__ bias1, float* __restrict__ out, int M, int Nn) {
  __shared__ float AsT[32][68];  // [kk][row], stride 68: 16B-aligned rows
  __shared__ float Bs[32][128];
  const int tid = threadIdx.x;
  const int tx = tid & 15;   // col group: cols tx*8..tx*8+7
  const int ty = tid >> 4;   // row group: rows ty*4..ty*4+3
  const int bm = blockIdx.x * 64;

  float acc[4][8];
#pragma unroll
  for (int i = 0; i < 4; i++)
#pragma unroll
    for (int j = 0; j < 8; j++) acc[i][j] = 0.f;

  for (int k0 = 0; k0 < K; k0 += 32) {
    // A tile: 64 rows x 32 cols = 512 float4, 2 per thread; store transposed
#pragma unroll
    for (int f = tid; f < 512; f += 256) {
      int r = f >> 3, c4 = f & 7;
      int row = bm + r;
      float4 v = make_float4(0.f, 0.f, 0.f, 0.f);
      if (row < M) v = *(const float4*)(A + (long long)row * K + k0 + c4 * 4);
      AsT[c4 * 4 + 0][r] = v.x;
      AsT[c4 * 4 + 1][r] = v.y;
      AsT[c4 * 4 + 2][r] = v.z;
      AsT[c4 * 4 + 3][r] = v.w;
    }
    // B tile: 32 rows x 128 cols = 1024 float4, 4 per thread
#pragma unroll
    for (int f = tid; f < 1024; f += 256) {
      int r = f >> 5, c4 = f & 31;
      int k = k0 + r;
      int c = c4 * 4;
      float4 v;
      if (!SPLIT) {
        v = *(const float4*)(B0 + (long long)k * 128 + c);
      } else {
        const float* Bp = (c < 64) ? (B0 + (long long)k * 64 + c)
                                   : (B1 + (long long)k * 64 + (c - 64));
        v = *(const float4*)Bp;
      }
      *(float4*)&Bs[r][c] = v;
    }
    __syncthreads();
#pragma unroll
    for (int kk = 0; kk < 32; kk++) {
      float4 av = *(const float4*)(&AsT[kk][ty * 4]);
      float4 b0 = *(const float4*)(&Bs[kk][tx * 8]);
      float4 b1 = *(const float4*)(&Bs[kk][tx * 8 + 4]);
      float a[4] = {av.x, av.y, av.z, av.w};
      float b[8] = {b0.x, b0.y, b0.z, b0.w, b1.x, b1.y, b1.z, b1.w};
#pragma unroll
      for (int i = 0; i < 4; i++)
#pragma unroll
        for (int j = 0; j < 8; j++) acc[i][j] = fmaf(a[i], b[j], acc[i][j]);
    }
    __syncthreads();
  }

#pragma unroll
  for (int i = 0; i < 4; i++) {
    int row = bm + ty * 4 + i;
    if (row >= M) continue;
    int c0 = tx * 8;  // 8-col group never crosses the 64-col boundary
    if (!SPLIT) {
      float4 v0 = make_float4(acc[i][0], acc[i][1], acc[i][2], acc[i][3]);
      float4 v1 = make_float4(acc[i][4], acc[i][5], acc[i][6], acc[i][7]);
      *(float4*)(out + (long long)row * 128 + c0) = v0;
      *(float4*)(out + (long long)row * 128 + c0 + 4) = v1;
    } else {
      const float* bb = (c0 < 64) ? bias0 : bias1;
      int cb = c0 & 63;
      long long base = (c0 < 64) ? ((long long)row * 64 + c0)
                                 : ((long long)Nn * 64 + (long long)row * 64 + (c0 - 64));
      float4 v0 = make_float4(acc[i][0] + bb[cb + 0], acc[i][1] + bb[cb + 1],
                              acc[i][2] + bb[cb + 2], acc[i][3] + bb[cb + 3]);
      float4 v1 = make_float4(acc[i][4] + bb[cb + 4], acc[i][5] + bb[cb + 5],
                              acc[i][6] + bb[cb + 6], acc[i][7] + bb[cb + 7]);
      *(float4*)(out + base) = v0;
      *(float4*)(out + base + 4) = v1;
    }
  }
}

// Wave-per-node CSR aggregation: out[n][c] = sum_{e in in(n)} feat[src(e)][c]
// Lane c loads float2 (channels 2c, 2c+1); edge loop unrolled x4 so each wave
// keeps 4 independent 512B loads in flight.
template <bool RELU>
__global__ __launch_bounds__(256) void seg_kernel(
    const float* __restrict__ feat, const int* __restrict__ offsets,
    const int* __restrict__ csr_src, const float* __restrict__ bias,
    float* __restrict__ out, int Nn) {
  int n = blockIdx.x * 4 + (threadIdx.x >> 6);
  int lane = threadIdx.x & 63;
  if (n >= Nn) return;
  int lo = offsets[n], hi = offsets[n + 1];
  int c = lane << 1;  // channel pair
  float ax = 0.f, ay = 0.f;
  int i = lo;
  for (; i + 4 <= hi; i += 4) {
    int s0 = csr_src[i];
    int s1 = csr_src[i + 1];
    int s2 = csr_src[i + 2];
    int s3 = csr_src[i + 3];
    float2 v0 = *(const float2*)(feat + (size_t)s0 * HIDC + c);
    float2 v1 = *(const float2*)(feat + (size_t)s1 * HIDC + c);
    float2 v2 = *(const float2*)(feat + (size_t)s2 * HIDC + c);
    float2 v3 = *(const float2*)(feat + (size_t)s3 * HIDC + c);
    ax += v0.x + v1.x + v2.x + v3.x;
    ay += v0.y + v1.y + v2.y + v3.y;
  }
  for (; i < hi; i++) {
    int s = csr_src[i];
    float2 v = *(const float2*)(feat + (size_t)s * HIDC + c);
    ax += v.x;
    ay += v.y;
  }
  if (RELU) {
    ax = fmaxf(ax + bias[c], 0.f);
    ay = fmaxf(ay + bias[c + 1], 0.f);
  }
  *(float2*)(out + (size_t)n * HIDC + c) = make_float2(ax, ay);
}

extern "C" void kernel_launch(void* const* d_in, const int* in_sizes, int n_in,
                              void* d_out, int out_size, void* d_ws, size_t ws_size,
                              hipStream_t stream) {
  const float* x  = (const float*)d_in[0];
  const void*  ei = d_in[1];
  const float* W1 = (const float*)d_in[2];
  const float* b1 = (const float*)d_in[3];
  const float* W2 = (const float*)d_in[4];
  const float* b2 = (const float*)d_in[5];
  const float* W3 = (const float*)d_in[6];
  const float* b3 = (const float*)d_in[7];
  float* out = (float*)d_out;

  const int Nn = in_sizes[0] / INC;  // 100000
  const int E  = in_sizes[1] / 2;    // 1600000

  const int SB = (Nn + 255) / 256;   // scan blocks (391 <= 512)

  // Workspace layout (~110 MB)
  float* h0 = (float*)d_ws;                         // Nn*128
  float* h  = h0 + (size_t)Nn * HIDC;               // Nn*128
  float* agg2 = h0;                                 // reuse h0 (dead after seg1)
  int* offsets = (int*)(h + (size_t)Nn * HIDC);     // Nn+1
  int* cnt     = offsets + (Nn + 1);                // Nn (counts, then cursor)
  int* csr     = cnt + Nn;                          // E
  int* flag    = csr + E;                           // 1
  int* bsums   = flag + 1;                          // SB
  int* bbase   = bsums + SB;                        // SB

  const int zb = (Nn + 255) / 256;
  const int eb = 2048;

  hipLaunchKernelGGL(detect_kernel, dim3(1), dim3(256), 0, stream,
                     (const unsigned int*)ei, flag);
  hipLaunchKernelGGL(zero_int_kernel, dim3(zb), dim3(256), 0, stream, cnt, Nn);
  hipLaunchKernelGGL(count_kernel, dim3(eb), dim3(256), 0, stream, ei, E, flag, cnt);
  hipLaunchKernelGGL(block_sum_kernel, dim3(SB), dim3(256), 0, stream, cnt, bsums, Nn);
  hipLaunchKernelGGL(scan_blocksums_kernel, dim3(1), dim3(512), 0, stream, bsums, bbase, SB);
  hipLaunchKernelGGL(scan_local_kernel, dim3(SB), dim3(256), 0, stream, cnt, bbase, offsets, Nn);
  hipLaunchKernelGGL(zero_int_kernel, dim3(zb), dim3(256), 0, stream, cnt, Nn);
  hipLaunchKernelGGL(fill_kernel, dim3(eb), dim3(256), 0, stream, ei, E, flag,
                     offsets, cnt, csr);

  const int mg = (Nn + 63) / 64;
  const int sg = (Nn + 3) / 4;
  hipLaunchKernelGGL((gemm_kernel<INC, false>), dim3(mg), dim3(256), 0, stream,
                     x, W1, nullptr, nullptr, nullptr, h0, Nn, Nn);
  hipLaunchKernelGGL((seg_kernel<true>), dim3(sg), dim3(256), 0, stream,
                     h0, offsets, csr, b1, h, Nn);
  hipLaunchKernelGGL((seg_kernel<false>), dim3(sg), dim3(256), 0, stream,
                     h, offsets, csr, nullptr, agg2, Nn);
  hipLaunchKernelGGL((gemm_kernel<HIDC, true>), dim3(mg), dim3(256), 0, stream,
                     agg2, W2, W3, b2, b3, out, Nn, Nn);
}